// Round 2
// baseline (1955.293 us; speedup 1.0000x reference)
//
#include <hip/hip_runtime.h>
#include <hip/hip_fp16.h>

#define H 4096
#define HH ((size_t)H * (size_t)H)
#define NBLK 768

#define OP_MUL  0
#define OP_TANH 1
#define OP_ADD  2

// ---------------------------------------------------------------------------
// Single persistent kernel, PLAIN launch (no cooperative API), hand-rolled
// grid barrier with explicit agent-scope atomics + fences (cross-XCD safe).
// ws float-slot layout (slot = H floats) after 192 MB of fp16 mats
// (W16 = L16[3] ++ R16[3]):
//  atomic (zeroed by memset): 0-2 xL | 3-5 hL | 6-8 hR | 9-11 rR | 12-14 z1R
//    15-17 rhR | 18-20 omzR | 21-23 z2hR | 24-26 htL | 27-29 zhL
//    30: scores (6 sets x 4 floats) at +0..23 ; grid-barrier vars at +32,+33
//  cands: 31-34 rh | 35-38 omz | 39-42 z2h | 43-46 ht | 47-50 zh | 51-54 hn
//  mixes: 57 rh | 58 omz | 59 z2h | 60 ht | 61 zh
//  candidate 3 is identity (L[3]=R[3]=I): gemvs run l in {0,1,2} only.
// Phases (9 grid barriers):
//  P1 f32 gemv L,R + fp16 convert | P2 rR,z1R | P3 cs2 |
//  P4 rhR,omzR,z2hR (+mixes 57-59, out-slots 0,2,4) | P5 ht cands |
//  P6 htL (+mix 60, out-slot 1) | P7 zh cands | P8 zhL (+mix 61, out-slot 3) |
//  P9 hn cands | P10 final mix -> dout
// ---------------------------------------------------------------------------

__device__ __forceinline__ float sigmoidf_(float v) {
  return 1.0f / (1.0f + __expf(-v));
}

// Hand-rolled grid barrier. bar[0] = arrive counter, bar[1] = generation.
// Requires all NBLK blocks co-resident (guaranteed: 3 blocks/CU x 256 CUs,
// enforced by __launch_bounds__(256,3); VGPR<=168, LDS ~1.3KB).
// __syncthreads drains each wave's stores to L2 (vmcnt(0) before s_barrier);
// thread0's __threadfence + agent-scope RMWs do the L2 writeback/invalidate.
__device__ __forceinline__ void gbar(unsigned* bar) {
  __syncthreads();
  if (threadIdx.x == 0) {
    __threadfence();   // agent release: write back this XCD's dirty L2
    unsigned g = __hip_atomic_load(bar + 1, __ATOMIC_RELAXED,
                                   __HIP_MEMORY_SCOPE_AGENT);
    unsigned a = __hip_atomic_fetch_add(bar, 1u, __ATOMIC_ACQ_REL,
                                        __HIP_MEMORY_SCOPE_AGENT);
    if (a == NBLK - 1u) {
      __hip_atomic_store(bar, 0u, __ATOMIC_RELAXED, __HIP_MEMORY_SCOPE_AGENT);
      __hip_atomic_fetch_add(bar + 1, 1u, __ATOMIC_RELEASE,
                             __HIP_MEMORY_SCOPE_AGENT);
    } else {
      while (__hip_atomic_load(bar + 1, __ATOMIC_ACQUIRE,
                               __HIP_MEMORY_SCOPE_AGENT) == g)
        __builtin_amdgcn_s_sleep(2);
    }
    __threadfence();   // agent acquire: invalidate L1/L2 before peer reads
  }
  __syncthreads();
}

template<int NW>
__device__ __forceinline__ void reduce_atomic(float* vals, float* sc, int tid) {
  __shared__ float red[4][NW];
  const int lane = tid & 63, wv = tid >> 6;
#pragma unroll
  for (int j = 0; j < NW; ++j) {
    float v = vals[j];
#pragma unroll
    for (int off = 32; off > 0; off >>= 1) v += __shfl_down(v, off);
    if (lane == 0) red[wv][j] = v;
  }
  __syncthreads();
  if (tid < NW)
    atomicAdd(sc + tid, red[0][tid] + red[1][tid] + red[2][tid] + red[3][tid]);
}

// round-1 fp32 gemv inner loop over 128 rows + fp16 conversion store.
template<int NV>
__device__ __forceinline__ void p1_loop(const float* __restrict__ Mp,
                                        __half* __restrict__ M16p,
                                        const float* __restrict__ vs,
                                        float* __restrict__ f,
                                        int slot0, int slot1, int k0) {
  float acc[NV][4];
#pragma unroll
  for (int v = 0; v < NV; ++v)
#pragma unroll
    for (int j = 0; j < 4; ++j) acc[v][j] = 0.0f;
#pragma unroll 4
  for (int hh = 0; hh < 128; ++hh) {
    float4 m4 = *reinterpret_cast<const float4*>(Mp + (size_t)hh * H);
    __half c[4] = {__float2half(m4.x), __float2half(m4.y),
                   __float2half(m4.z), __float2half(m4.w)};
    *reinterpret_cast<uint2*>(M16p + (size_t)hh * H) =
        *reinterpret_cast<const uint2*>(c);
#pragma unroll
    for (int v = 0; v < NV; ++v) {
      const float s = vs[v * 128 + hh];
      acc[v][0] = fmaf(s, m4.x, acc[v][0]);
      acc[v][1] = fmaf(s, m4.y, acc[v][1]);
      acc[v][2] = fmaf(s, m4.z, acc[v][2]);
      acc[v][3] = fmaf(s, m4.w, acc[v][3]);
    }
  }
  const int slots[2] = {slot0, slot1};
#pragma unroll
  for (int v = 0; v < NV; ++v)
#pragma unroll
    for (int j = 0; j < 4; ++j)
      atomicAdd(f + (size_t)slots[v] * H + k0 + j, acc[v][j]);
}

// fp16 gemv inner loop over 64 rows; atomics into ob + (v*3+m)*H + k.
template<int NV>
__device__ __forceinline__ void gemv16_core(const __half* __restrict__ Mp,
                                            const float* __restrict__ vs,
                                            float* __restrict__ ob,
                                            int m, int k0) {
  float acc[NV][8];
#pragma unroll
  for (int v = 0; v < NV; ++v)
#pragma unroll
    for (int j = 0; j < 8; ++j) acc[v][j] = 0.0f;
#pragma unroll 4
  for (int hh = 0; hh < 64; ++hh) {
    union { uint4 u; __half2 h2[4]; } cv;
    cv.u = *reinterpret_cast<const uint4*>(Mp + (size_t)hh * H);
    float fr[8];
#pragma unroll
    for (int j = 0; j < 4; ++j) {
      float2 tt = __half22float2(cv.h2[j]);
      fr[2 * j] = tt.x; fr[2 * j + 1] = tt.y;
    }
#pragma unroll
    for (int v = 0; v < NV; ++v) {
      const float s = vs[v * 64 + hh];
#pragma unroll
      for (int j = 0; j < 8; ++j) acc[v][j] = fmaf(s, fr[j], acc[v][j]);
    }
  }
#pragma unroll
  for (int v = 0; v < NV; ++v)
#pragma unroll
    for (int j = 0; j < 8; ++j)
      atomicAdd(ob + (size_t)(v * 3 + m) * H + k0 + j, acc[v][j]);
}

// softmax-mix NV candidate sets for rows [r0,r0+64) into vs (and mix slots).
template<int NV>
__device__ __forceinline__ void stage_mix(const float* __restrict__ scb,
                                          const float* __restrict__ candb,
                                          float* __restrict__ vs,
                                          float* __restrict__ mixst,
                                          int r0, int t) {
  if (t < 64) {
    const int h = r0 + t;
#pragma unroll
    for (int v = 0; v < NV; ++v) {
      const float* s4 = scb + v * 4;
      float s0 = s4[0], s1 = s4[1], s2 = s4[2], s3 = s4[3];
      float mx = fmaxf(fmaxf(s0, s1), fmaxf(s2, s3));
      float e0 = __expf(s0 - mx), e1 = __expf(s1 - mx);
      float e2 = __expf(s2 - mx), e3 = __expf(s3 - mx);
      float inv = 1.0f / (e0 + e1 + e2 + e3);
      const float* cb = candb + (size_t)v * 4 * H + h;
      float mix = (e0 * cb[0] + e1 * cb[H] + e2 * cb[2 * (size_t)H] +
                   e3 * cb[3 * (size_t)H]) * inv;
      vs[v * 64 + t] = mix;
      if (mixst) mixst[(size_t)v * H + h] = mix;
    }
  }
}

__device__ __forceinline__ void write_im(const float* __restrict__ s4,
                                         float* __restrict__ dout, int os) {
  float s[4] = {s4[0], s4[1], s4[2], s4[3]};
  int idx = 0; float mx = s[0];
  for (int q = 1; q < 4; ++q) if (s[q] > mx) { mx = s[q]; idx = q; }
  float second = -1e30f;
  for (int q = 0; q < 4; ++q) if (q != idx && s[q] > second) second = s[q];
  dout[H + 3 + os] = (float)idx;
  dout[H + 9 + os] = mx - second;
}

// generic candidate+score phase: c_l = op(A_l, B_l, b_l), blocks b<16 x 256.
template<int OP>
__device__ __forceinline__ void csx_phase(const float* __restrict__ A,
                                          const float* __restrict__ A3,
                                          const float* __restrict__ B,
                                          const float* __restrict__ B3,
                                          const float* __restrict__ bias,
                                          const float* __restrict__ Ws,
                                          float* __restrict__ cand,
                                          float* __restrict__ scdst,
                                          int h, int t) {
  const float ws = Ws[h];
  float c[4];
#pragma unroll
  for (int l = 0; l < 4; ++l) {
    const float a  = (l < 3) ? A[(size_t)l * H + h] : A3[h];
    const float bv = (l < 3) ? B[(size_t)l * H + h] : B3[h];
    const float bl = bias[(size_t)l * H + h];
    if (OP == OP_MUL)  c[l] = fmaf(a, bv, bl);
    if (OP == OP_TANH) c[l] = tanhf(a + bv + bl);
    if (OP == OP_ADD)  c[l] = a + bv + bl;
    cand[(size_t)l * H + h] = c[l];
  }
  float vals[4] = {c[0] * ws, c[1] * ws, c[2] * ws, c[3] * ws};
  reduce_atomic<4>(vals, scdst, t);
}

__global__ __launch_bounds__(256, 3) void mega_k(
    const float* __restrict__ x, const float* __restrict__ hprev,
    const float* __restrict__ L, const float* __restrict__ R,
    const float* __restrict__ bias, const float* __restrict__ Ws,
    float* __restrict__ dout, __half* __restrict__ W16,
    float* __restrict__ f) {
  const int b = blockIdx.x;
  const int t = threadIdx.x;
  __shared__ float smem[256];
  const __half* R16 = W16 + 3 * HH;
  float* sc = f + 30 * (size_t)H;
  unsigned* bar = reinterpret_cast<unsigned*>(f + 30 * (size_t)H + 32);

  // ---- P1: round 1 fp32 gemv (xL,hL from L; hR from R) + fp16 convert ----
  // 768 blocks: mat(6) x kt(4) x rowchunk(32 of 128 rows). Perfectly balanced.
  {
    const int mat = b >> 7;            // 0..5 (0-2 = L, 3-5 = R)
    const int kt  = (b >> 5) & 3;
    const int r0  = (b & 31) << 7;     // 128 rows per block
    const int k0  = (kt << 10) + (t << 2);
    if (mat < 3) {
      smem[t] = (t < 128) ? x[r0 + t] : hprev[r0 + t - 128];
    } else if (t < 128) {
      smem[t] = hprev[r0 + t];
    }
    __syncthreads();
    const size_t off = (size_t)r0 * H + k0;
    __half* M16p = W16 + (size_t)mat * HH + off;
    if (mat < 3) {
      // v0 = x -> slot mat (xL), v1 = hprev -> slot 3+mat (hL)
      p1_loop<2>(L + (size_t)mat * HH + off, M16p, smem, f, mat, 3 + mat, k0);
    } else {
      // v0 = hprev -> slot 3+mat = 6..8 (hR)
      p1_loop<1>(R + (size_t)(mat - 3) * HH + off, M16p, smem, f, 3 + mat, 0, k0);
    }
  }
  gbar(bar);

  // ---- P2: rR, z1R (r/z1 computed inline from round-1 slots) ----
  // 384 blocks: mat(3) x kt(2) x rowchunk(64 of 64 rows).
  if (b < 384) {
    const int m = b >> 7, kt = (b >> 6) & 1, rcg = b & 63;
    const int r0 = rcg << 6;
    const int k0 = (kt << 11) + (t << 3);
    if (t < 64) {
      const int h = r0 + t;
      // r  = sigmoid(xL[1]+hR[1]+b[1]) ; z1 = sigmoid(xL[0]+hR[0]+b[0])
      smem[t]      = sigmoidf_(f[(size_t)1 * H + h] + f[(size_t)7 * H + h] + bias[H + h]);
      smem[64 + t] = sigmoidf_(f[h] + f[(size_t)6 * H + h] + bias[h]);
    }
    __syncthreads();
    gemv16_core<2>(R16 + (size_t)m * HH + (size_t)r0 * H + k0, smem,
                   f + (size_t)9 * H, m, k0);   // v0->9+m (rR), v1->12+m (z1R)
  }
  gbar(bar);

  // ---- P3: cs2 — rh/omz/z2h candidates + scores ----
  if (b < 16) {
    const int h = (b << 8) + t;
    const float hp_ = hprev[h];
    const float r3 = sigmoidf_(f[(size_t)1 * H + h] + f[(size_t)7 * H + h] + bias[H + h]);
    const float z3 = sigmoidf_(f[h] + f[(size_t)6 * H + h] + bias[h]);
    const float ws = Ws[h];
    float vals[12];
#pragma unroll
    for (int l = 0; l < 3; ++l) {
      const float hl = f[(size_t)(3 + l) * H + h];
      const float rr = f[(size_t)(9 + l) * H + h];
      const float zz = f[(size_t)(12 + l) * H + h];
      const float bl = bias[(size_t)l * H + h];
      const float crh = fmaf(hl, rr, bl);
      const float com = 1.0f - (zz + bl);
      const float cz2 = fmaf(hl, zz, bl);
      f[(size_t)(31 + l) * H + h] = crh;
      f[(size_t)(35 + l) * H + h] = com;
      f[(size_t)(39 + l) * H + h] = cz2;
      vals[l] = crh * ws; vals[4 + l] = com * ws; vals[8 + l] = cz2 * ws;
    }
    {
      const float bl = bias[(size_t)3 * H + h];
      const float crh = fmaf(hp_, r3, bl);
      const float com = 1.0f - (z3 + bl);
      const float cz2 = fmaf(hp_, z3, bl);
      f[(size_t)34 * H + h] = crh;
      f[(size_t)38 * H + h] = com;
      f[(size_t)42 * H + h] = cz2;
      vals[3] = crh * ws; vals[7] = com * ws; vals[11] = cz2 * ws;
    }
    reduce_atomic<12>(vals, sc, t);
  }
  gbar(bar);

  // ---- P4: rhR, omzR, z2hR (mix staging inline; mixes -> 57-59) ----
  if (b < 384) {
    const int m = b >> 7, kt = (b >> 6) & 1, rcg = b & 63;
    const int r0 = rcg << 6;
    const int k0 = (kt << 11) + (t << 3);
    stage_mix<3>(sc, f + (size_t)31 * H, smem,
                 (m == 0 && kt == 0) ? f + (size_t)57 * H : nullptr, r0, t);
    if (b == 0 && t == 0) {
      write_im(sc, dout, 0);       // rh  -> i0/m0
      write_im(sc + 4, dout, 2);   // omz -> i2/m2
      write_im(sc + 8, dout, 4);   // z2h -> i4/m4
    }
    __syncthreads();
    gemv16_core<3>(R16 + (size_t)m * HH + (size_t)r0 * H + k0, smem,
                   f + (size_t)15 * H, m, k0);  // 15-17 rhR, 18-20 omzR, 21-23 z2hR
  }
  gbar(bar);

  // ---- P5: h_tilde cands = tanh(xL + rhR + b) ----
  if (b < 16) {
    const int h = (b << 8) + t;
    csx_phase<OP_TANH>(f, x, f + (size_t)15 * H, f + (size_t)57 * H,
                       bias, Ws, f + (size_t)43 * H, sc + 12, h, t);
  }
  gbar(bar);

  // ---- P6: htL = L * mix(ht) ; mix -> 60, out-slot 1 ----
  if (b < 384) {
    const int m = b >> 7, kt = (b >> 6) & 1, rcg = b & 63;
    const int r0 = rcg << 6;
    const int k0 = (kt << 11) + (t << 3);
    stage_mix<1>(sc + 12, f + (size_t)43 * H, smem,
                 (m == 0 && kt == 0) ? f + (size_t)60 * H : nullptr, r0, t);
    if (b == 0 && t == 0) write_im(sc + 12, dout, 1);
    __syncthreads();
    gemv16_core<1>(W16 + (size_t)m * HH + (size_t)r0 * H + k0, smem,
                   f + (size_t)24 * H, m, k0);  // 24-26 htL
  }
  gbar(bar);

  // ---- P7: zh cands = htL * omzR + b ----
  if (b < 16) {
    const int h = (b << 8) + t;
    csx_phase<OP_MUL>(f + (size_t)24 * H, f + (size_t)60 * H,
                      f + (size_t)18 * H, f + (size_t)58 * H,
                      bias, Ws, f + (size_t)47 * H, sc + 16, h, t);
  }
  gbar(bar);

  // ---- P8: zhL = L * mix(zh) ; mix -> 61, out-slot 3 ----
  if (b < 384) {
    const int m = b >> 7, kt = (b >> 6) & 1, rcg = b & 63;
    const int r0 = rcg << 6;
    const int k0 = (kt << 11) + (t << 3);
    stage_mix<1>(sc + 16, f + (size_t)47 * H, smem,
                 (m == 0 && kt == 0) ? f + (size_t)61 * H : nullptr, r0, t);
    if (b == 0 && t == 0) write_im(sc + 16, dout, 3);
    __syncthreads();
    gemv16_core<1>(W16 + (size_t)m * HH + (size_t)r0 * H + k0, smem,
                   f + (size_t)27 * H, m, k0);  // 27-29 zhL
  }
  gbar(bar);

  // ---- P9: hn cands = zhL + z2hR + b ----
  if (b < 16) {
    const int h = (b << 8) + t;
    csx_phase<OP_ADD>(f + (size_t)27 * H, f + (size_t)61 * H,
                      f + (size_t)21 * H, f + (size_t)59 * H,
                      bias, Ws, f + (size_t)51 * H, sc + 20, h, t);
  }
  gbar(bar);

  // ---- P10: final mix -> dout ----
  if (b < 16) {
    const int h = (b << 8) + t;
    const float* s4 = sc + 20;
    float s0 = s4[0], s1 = s4[1], s2 = s4[2], s3 = s4[3];
    float mx = fmaxf(fmaxf(s0, s1), fmaxf(s2, s3));
    float e0 = __expf(s0 - mx), e1 = __expf(s1 - mx);
    float e2 = __expf(s2 - mx), e3 = __expf(s3 - mx);
    float inv = 1.0f / (e0 + e1 + e2 + e3);
    const float* cb = f + (size_t)51 * H + h;
    dout[h] = (e0 * cb[0] + e1 * cb[H] + e2 * cb[2 * (size_t)H] +
               e3 * cb[3 * (size_t)H]) * inv;
    if (b == 0 && t == 0) {
      dout[H + 0] = 0.f; dout[H + 1] = 1.f; dout[H + 2] = 0.f;
      write_im(sc + 20, dout, 5);
    }
  }
}

extern "C" void kernel_launch(void* const* d_in, const int* in_sizes, int n_in,
                              void* d_out, int out_size, void* d_ws, size_t ws_size,
                              hipStream_t stream) {
  const float* x  = (const float*)d_in[0];
  const float* hp = (const float*)d_in[1];
  const float* L  = (const float*)d_in[2];
  const float* R  = (const float*)d_in[3];
  const float* bb = (const float*)d_in[4];
  const float* Ws = (const float*)d_in[5];
  float* out = (float*)d_out;

  __half* W16 = (__half*)d_ws;                       // 6*H*H halfs (L16 ++ R16)
  float*  f   = (float*)(W16 + 6 * HH);              // slot region

  // zero atomic accumulators (slots 0..30) + barrier vars (slot30 tail).
  // ws is re-poisoned between replays, so this must run every launch.
  hipMemsetAsync(f, 0, (size_t)31 * H * sizeof(float), stream);

  mega_k<<<dim3(NBLK), dim3(256), 0, stream>>>(x, hp, L, R, bb, Ws,
                                               out, W16, f);
}

// Round 3
// 857.729 us; speedup vs baseline: 2.2796x; 2.2796x over previous
//
#include <hip/hip_runtime.h>
#include <hip/hip_fp16.h>

#define H 4096
#define HH ((size_t)H * (size_t)H)
#define NBLK 768

#define OP_MUL  0
#define OP_TANH 1
#define OP_ADD  2

// ---------------------------------------------------------------------------
// Single persistent kernel, PLAIN launch. Grid barrier v2:
//  - arrival: striped relaxed agent-scope RMWs (8 cache lines/barrier)
//  - wait: RELAXED agent-scope polls (cache-bypass load, NO buffer_inv storm)
//  - exactly one release fence before arrival + one acquire fence after wait
//  - dedicated zeroed storage per barrier (no generation/reset logic)
//  - blocks >= 384 exit after the P1 barrier (targets: 768 then 384)
// ws float-slot layout (slot = H floats) after 192 MB of fp16 mats
// (W16 = L16[3] ++ R16[3]):
//  atomic (zeroed by memset): 0-2 xL | 3-5 hL | 6-8 hR | 9-11 rR | 12-14 z1R
//    15-17 rhR | 18-20 omzR | 21-23 z2hR | 24-26 htL | 27-29 zhL
//    30: scores (6 sets x 4 floats) at +0..23 ; barrier area at +256..
//  cands: 31-34 rh | 35-38 omz | 39-42 z2h | 43-46 ht | 47-50 zh | 51-54 hn
//  mixes: 57 rh | 58 omz | 59 z2h | 60 ht | 61 zh
//  candidate 3 is identity (L[3]=R[3]=I): gemvs run l in {0,1,2} only.
// Phases (9 barriers):
//  P1 f32 gemv L,R + fp16 convert | P2 rR,z1R | P3 cs2 |
//  P4 rhR,omzR,z2hR (+mixes 57-59, out-slots 0,2,4) | P5 ht cands |
//  P6 htL (+mix 60, out-slot 1) | P7 zh cands | P8 zhL (+mix 61, out-slot 3) |
//  P9 hn cands | P10 final mix -> dout
// ---------------------------------------------------------------------------

__device__ __forceinline__ float sigmoidf_(float v) {
  return 1.0f / (1.0f + __expf(-v));
}

// Barrier storage: per barrier 144 uints (8 stripes on own 64B lines + gen
// line at +128). All zeroed by the launch-side memset each replay.
__device__ __forceinline__ void gbar(unsigned* base, unsigned target, int b) {
  __syncthreads();
  if (threadIdx.x == 0) {
    // one release fence: write back this XCD's dirty L2 so peers can read
    __builtin_amdgcn_fence(__ATOMIC_RELEASE, "agent");
    __hip_atomic_fetch_add(base + ((b & 7) << 4), 1u, __ATOMIC_RELAXED,
                           __HIP_MEMORY_SCOPE_AGENT);
    if (b == 0) {
      unsigned sum;
      do {
        sum = 0;
#pragma unroll
        for (int s = 0; s < 8; ++s)
          sum += __hip_atomic_load(base + (s << 4), __ATOMIC_RELAXED,
                                   __HIP_MEMORY_SCOPE_AGENT);
        if (sum < target) __builtin_amdgcn_s_sleep(4);
      } while (sum < target);
      __hip_atomic_store(base + 128, 1u, __ATOMIC_RELAXED,
                         __HIP_MEMORY_SCOPE_AGENT);
    } else {
      // RELAXED poll: cache-bypass read, no L2 invalidate per iteration
      while (__hip_atomic_load(base + 128, __ATOMIC_RELAXED,
                               __HIP_MEMORY_SCOPE_AGENT) == 0u)
        __builtin_amdgcn_s_sleep(4);
    }
    // one acquire fence: drop stale L1/L2 lines before reading peers' data
    __builtin_amdgcn_fence(__ATOMIC_ACQUIRE, "agent");
  }
  __syncthreads();
}

template<int NW>
__device__ __forceinline__ void reduce_atomic(float* vals, float* sc, int tid) {
  __shared__ float red[4][NW];
  const int lane = tid & 63, wv = tid >> 6;
#pragma unroll
  for (int j = 0; j < NW; ++j) {
    float v = vals[j];
#pragma unroll
    for (int off = 32; off > 0; off >>= 1) v += __shfl_down(v, off);
    if (lane == 0) red[wv][j] = v;
  }
  __syncthreads();
  if (tid < NW)
    atomicAdd(sc + tid, red[0][tid] + red[1][tid] + red[2][tid] + red[3][tid]);
}

// round-1 fp32 gemv inner loop over 128 rows + fp16 conversion store.
template<int NV>
__device__ __forceinline__ void p1_loop(const float* __restrict__ Mp,
                                        __half* __restrict__ M16p,
                                        const float* __restrict__ vs,
                                        float* __restrict__ f,
                                        int slot0, int slot1, int k0) {
  float acc[NV][4];
#pragma unroll
  for (int v = 0; v < NV; ++v)
#pragma unroll
    for (int j = 0; j < 4; ++j) acc[v][j] = 0.0f;
#pragma unroll 4
  for (int hh = 0; hh < 128; ++hh) {
    float4 m4 = *reinterpret_cast<const float4*>(Mp + (size_t)hh * H);
    __half c[4] = {__float2half(m4.x), __float2half(m4.y),
                   __float2half(m4.z), __float2half(m4.w)};
    *reinterpret_cast<uint2*>(M16p + (size_t)hh * H) =
        *reinterpret_cast<const uint2*>(c);
#pragma unroll
    for (int v = 0; v < NV; ++v) {
      const float s = vs[v * 128 + hh];
      acc[v][0] = fmaf(s, m4.x, acc[v][0]);
      acc[v][1] = fmaf(s, m4.y, acc[v][1]);
      acc[v][2] = fmaf(s, m4.z, acc[v][2]);
      acc[v][3] = fmaf(s, m4.w, acc[v][3]);
    }
  }
  const int slots[2] = {slot0, slot1};
#pragma unroll
  for (int v = 0; v < NV; ++v)
#pragma unroll
    for (int j = 0; j < 4; ++j)
      atomicAdd(f + (size_t)slots[v] * H + k0 + j, acc[v][j]);
}

// fp16 gemv inner loop over 64 rows; atomics into ob + (v*3+m)*H + k.
template<int NV>
__device__ __forceinline__ void gemv16_core(const __half* __restrict__ Mp,
                                            const float* __restrict__ vs,
                                            float* __restrict__ ob,
                                            int m, int k0) {
  float acc[NV][8];
#pragma unroll
  for (int v = 0; v < NV; ++v)
#pragma unroll
    for (int j = 0; j < 8; ++j) acc[v][j] = 0.0f;
#pragma unroll 4
  for (int hh = 0; hh < 64; ++hh) {
    union { uint4 u; __half2 h2[4]; } cv;
    cv.u = *reinterpret_cast<const uint4*>(Mp + (size_t)hh * H);
    float fr[8];
#pragma unroll
    for (int j = 0; j < 4; ++j) {
      float2 tt = __half22float2(cv.h2[j]);
      fr[2 * j] = tt.x; fr[2 * j + 1] = tt.y;
    }
#pragma unroll
    for (int v = 0; v < NV; ++v) {
      const float s = vs[v * 64 + hh];
#pragma unroll
      for (int j = 0; j < 8; ++j) acc[v][j] = fmaf(s, fr[j], acc[v][j]);
    }
  }
#pragma unroll
  for (int v = 0; v < NV; ++v)
#pragma unroll
    for (int j = 0; j < 8; ++j)
      atomicAdd(ob + (size_t)(v * 3 + m) * H + k0 + j, acc[v][j]);
}

// softmax-mix NV candidate sets for rows [r0,r0+64) into vs (and mix slots).
template<int NV>
__device__ __forceinline__ void stage_mix(const float* __restrict__ scb,
                                          const float* __restrict__ candb,
                                          float* __restrict__ vs,
                                          float* __restrict__ mixst,
                                          int r0, int t) {
  if (t < 64) {
    const int h = r0 + t;
#pragma unroll
    for (int v = 0; v < NV; ++v) {
      const float* s4 = scb + v * 4;
      float s0 = s4[0], s1 = s4[1], s2 = s4[2], s3 = s4[3];
      float mx = fmaxf(fmaxf(s0, s1), fmaxf(s2, s3));
      float e0 = __expf(s0 - mx), e1 = __expf(s1 - mx);
      float e2 = __expf(s2 - mx), e3 = __expf(s3 - mx);
      float inv = 1.0f / (e0 + e1 + e2 + e3);
      const float* cb = candb + (size_t)v * 4 * H + h;
      float mix = (e0 * cb[0] + e1 * cb[H] + e2 * cb[2 * (size_t)H] +
                   e3 * cb[3 * (size_t)H]) * inv;
      vs[v * 64 + t] = mix;
      if (mixst) mixst[(size_t)v * H + h] = mix;
    }
  }
}

__device__ __forceinline__ void write_im(const float* __restrict__ s4,
                                         float* __restrict__ dout, int os) {
  float s[4] = {s4[0], s4[1], s4[2], s4[3]};
  int idx = 0; float mx = s[0];
  for (int q = 1; q < 4; ++q) if (s[q] > mx) { mx = s[q]; idx = q; }
  float second = -1e30f;
  for (int q = 0; q < 4; ++q) if (q != idx && s[q] > second) second = s[q];
  dout[H + 3 + os] = (float)idx;
  dout[H + 9 + os] = mx - second;
}

// generic candidate+score phase: c_l = op(A_l, B_l, b_l), blocks b<16 x 256.
template<int OP>
__device__ __forceinline__ void csx_phase(const float* __restrict__ A,
                                          const float* __restrict__ A3,
                                          const float* __restrict__ B,
                                          const float* __restrict__ B3,
                                          const float* __restrict__ bias,
                                          const float* __restrict__ Ws,
                                          float* __restrict__ cand,
                                          float* __restrict__ scdst,
                                          int h, int t) {
  const float ws = Ws[h];
  float c[4];
#pragma unroll
  for (int l = 0; l < 4; ++l) {
    const float a  = (l < 3) ? A[(size_t)l * H + h] : A3[h];
    const float bv = (l < 3) ? B[(size_t)l * H + h] : B3[h];
    const float bl = bias[(size_t)l * H + h];
    if (OP == OP_MUL)  c[l] = fmaf(a, bv, bl);
    if (OP == OP_TANH) c[l] = tanhf(a + bv + bl);
    if (OP == OP_ADD)  c[l] = a + bv + bl;
    cand[(size_t)l * H + h] = c[l];
  }
  float vals[4] = {c[0] * ws, c[1] * ws, c[2] * ws, c[3] * ws};
  reduce_atomic<4>(vals, scdst, t);
}

__global__ __launch_bounds__(256, 3) void mega_k(
    const float* __restrict__ x, const float* __restrict__ hprev,
    const float* __restrict__ L, const float* __restrict__ R,
    const float* __restrict__ bias, const float* __restrict__ Ws,
    float* __restrict__ dout, __half* __restrict__ W16,
    float* __restrict__ f) {
  const int b = blockIdx.x;
  const int t = threadIdx.x;
  __shared__ float smem[256];
  const __half* R16 = W16 + 3 * HH;
  float* sc = f + 30 * (size_t)H;
  unsigned* barb = reinterpret_cast<unsigned*>(f + 30 * (size_t)H + 256);
  // barrier i storage: barb + i*144 (8 stripe lines + gen line at +128)

  // ---- P1: round 1 fp32 gemv (xL,hL from L; hR from R) + fp16 convert ----
  // 768 blocks: mat(6) x kt(4) x rowchunk(32 of 128 rows). Perfectly balanced.
  {
    const int mat = b >> 7;            // 0..5 (0-2 = L, 3-5 = R)
    const int kt  = (b >> 5) & 3;
    const int r0  = (b & 31) << 7;     // 128 rows per block
    const int k0  = (kt << 10) + (t << 2);
    if (mat < 3) {
      smem[t] = (t < 128) ? x[r0 + t] : hprev[r0 + t - 128];
    } else if (t < 128) {
      smem[t] = hprev[r0 + t];
    }
    __syncthreads();
    const size_t off = (size_t)r0 * H + k0;
    __half* M16p = W16 + (size_t)mat * HH + off;
    if (mat < 3) {
      // v0 = x -> slot mat (xL), v1 = hprev -> slot 3+mat (hL)
      p1_loop<2>(L + (size_t)mat * HH + off, M16p, smem, f, mat, 3 + mat, k0);
    } else {
      // v0 = hprev -> slot 3+mat = 6..8 (hR)
      p1_loop<1>(R + (size_t)(mat - 3) * HH + off, M16p, smem, f, 3 + mat, 0, k0);
    }
  }
  gbar(barb, NBLK, b);
  if (b >= 384) return;   // blocks 384..767 have no further work

  // ---- P2: rR, z1R (r/z1 computed inline from round-1 slots) ----
  // 384 blocks: mat(3) x kt(2) x rowchunk(64 of 64 rows).
  {
    const int m = b >> 7, kt = (b >> 6) & 1, rcg = b & 63;
    const int r0 = rcg << 6;
    const int k0 = (kt << 11) + (t << 3);
    if (t < 64) {
      const int h = r0 + t;
      // r  = sigmoid(xL[1]+hR[1]+b[1]) ; z1 = sigmoid(xL[0]+hR[0]+b[0])
      smem[t]      = sigmoidf_(f[(size_t)1 * H + h] + f[(size_t)7 * H + h] + bias[H + h]);
      smem[64 + t] = sigmoidf_(f[h] + f[(size_t)6 * H + h] + bias[h]);
    }
    __syncthreads();
    gemv16_core<2>(R16 + (size_t)m * HH + (size_t)r0 * H + k0, smem,
                   f + (size_t)9 * H, m, k0);   // v0->9+m (rR), v1->12+m (z1R)
  }
  gbar(barb + 144, 384, b);

  // ---- P3: cs2 — rh/omz/z2h candidates + scores ----
  if (b < 16) {
    const int h = (b << 8) + t;
    const float hp_ = hprev[h];
    const float r3 = sigmoidf_(f[(size_t)1 * H + h] + f[(size_t)7 * H + h] + bias[H + h]);
    const float z3 = sigmoidf_(f[h] + f[(size_t)6 * H + h] + bias[h]);
    const float ws = Ws[h];
    float vals[12];
#pragma unroll
    for (int l = 0; l < 3; ++l) {
      const float hl = f[(size_t)(3 + l) * H + h];
      const float rr = f[(size_t)(9 + l) * H + h];
      const float zz = f[(size_t)(12 + l) * H + h];
      const float bl = bias[(size_t)l * H + h];
      const float crh = fmaf(hl, rr, bl);
      const float com = 1.0f - (zz + bl);
      const float cz2 = fmaf(hl, zz, bl);
      f[(size_t)(31 + l) * H + h] = crh;
      f[(size_t)(35 + l) * H + h] = com;
      f[(size_t)(39 + l) * H + h] = cz2;
      vals[l] = crh * ws; vals[4 + l] = com * ws; vals[8 + l] = cz2 * ws;
    }
    {
      const float bl = bias[(size_t)3 * H + h];
      const float crh = fmaf(hp_, r3, bl);
      const float com = 1.0f - (z3 + bl);
      const float cz2 = fmaf(hp_, z3, bl);
      f[(size_t)34 * H + h] = crh;
      f[(size_t)38 * H + h] = com;
      f[(size_t)42 * H + h] = cz2;
      vals[3] = crh * ws; vals[7] = com * ws; vals[11] = cz2 * ws;
    }
    reduce_atomic<12>(vals, sc, t);
  }
  gbar(barb + 2 * 144, 384, b);

  // ---- P4: rhR, omzR, z2hR (mix staging inline; mixes -> 57-59) ----
  {
    const int m = b >> 7, kt = (b >> 6) & 1, rcg = b & 63;
    const int r0 = rcg << 6;
    const int k0 = (kt << 11) + (t << 3);
    stage_mix<3>(sc, f + (size_t)31 * H, smem,
                 (m == 0 && kt == 0) ? f + (size_t)57 * H : nullptr, r0, t);
    if (b == 0 && t == 0) {
      write_im(sc, dout, 0);       // rh  -> i0/m0
      write_im(sc + 4, dout, 2);   // omz -> i2/m2
      write_im(sc + 8, dout, 4);   // z2h -> i4/m4
    }
    __syncthreads();
    gemv16_core<3>(R16 + (size_t)m * HH + (size_t)r0 * H + k0, smem,
                   f + (size_t)15 * H, m, k0);  // 15-17 rhR, 18-20 omzR, 21-23 z2hR
  }
  gbar(barb + 3 * 144, 384, b);

  // ---- P5: h_tilde cands = tanh(xL + rhR + b) ----
  if (b < 16) {
    const int h = (b << 8) + t;
    csx_phase<OP_TANH>(f, x, f + (size_t)15 * H, f + (size_t)57 * H,
                       bias, Ws, f + (size_t)43 * H, sc + 12, h, t);
  }
  gbar(barb + 4 * 144, 384, b);

  // ---- P6: htL = L * mix(ht) ; mix -> 60, out-slot 1 ----
  {
    const int m = b >> 7, kt = (b >> 6) & 1, rcg = b & 63;
    const int r0 = rcg << 6;
    const int k0 = (kt << 11) + (t << 3);
    stage_mix<1>(sc + 12, f + (size_t)43 * H, smem,
                 (m == 0 && kt == 0) ? f + (size_t)60 * H : nullptr, r0, t);
    if (b == 0 && t == 0) write_im(sc + 12, dout, 1);
    __syncthreads();
    gemv16_core<1>(W16 + (size_t)m * HH + (size_t)r0 * H + k0, smem,
                   f + (size_t)24 * H, m, k0);  // 24-26 htL
  }
  gbar(barb + 5 * 144, 384, b);

  // ---- P7: zh cands = htL * omzR + b ----
  if (b < 16) {
    const int h = (b << 8) + t;
    csx_phase<OP_MUL>(f + (size_t)24 * H, f + (size_t)60 * H,
                      f + (size_t)18 * H, f + (size_t)58 * H,
                      bias, Ws, f + (size_t)47 * H, sc + 16, h, t);
  }
  gbar(barb + 6 * 144, 384, b);

  // ---- P8: zhL = L * mix(zh) ; mix -> 61, out-slot 3 ----
  {
    const int m = b >> 7, kt = (b >> 6) & 1, rcg = b & 63;
    const int r0 = rcg << 6;
    const int k0 = (kt << 11) + (t << 3);
    stage_mix<1>(sc + 16, f + (size_t)47 * H, smem,
                 (m == 0 && kt == 0) ? f + (size_t)61 * H : nullptr, r0, t);
    if (b == 0 && t == 0) write_im(sc + 16, dout, 3);
    __syncthreads();
    gemv16_core<1>(W16 + (size_t)m * HH + (size_t)r0 * H + k0, smem,
                   f + (size_t)27 * H, m, k0);  // 27-29 zhL
  }
  gbar(barb + 7 * 144, 384, b);

  // ---- P9: hn cands = zhL + z2hR + b ----
  if (b < 16) {
    const int h = (b << 8) + t;
    csx_phase<OP_ADD>(f + (size_t)27 * H, f + (size_t)61 * H,
                      f + (size_t)21 * H, f + (size_t)59 * H,
                      bias, Ws, f + (size_t)51 * H, sc + 20, h, t);
  }
  gbar(barb + 8 * 144, 384, b);

  // ---- P10: final mix -> dout ----
  if (b < 16) {
    const int h = (b << 8) + t;
    const float* s4 = sc + 20;
    float s0 = s4[0], s1 = s4[1], s2 = s4[2], s3 = s4[3];
    float mx = fmaxf(fmaxf(s0, s1), fmaxf(s2, s3));
    float e0 = __expf(s0 - mx), e1 = __expf(s1 - mx);
    float e2 = __expf(s2 - mx), e3 = __expf(s3 - mx);
    float inv = 1.0f / (e0 + e1 + e2 + e3);
    const float* cb = f + (size_t)51 * H + h;
    dout[h] = (e0 * cb[0] + e1 * cb[H] + e2 * cb[2 * (size_t)H] +
               e3 * cb[3 * (size_t)H]) * inv;
    if (b == 0 && t == 0) {
      dout[H + 0] = 0.f; dout[H + 1] = 1.f; dout[H + 2] = 0.f;
      write_im(sc + 20, dout, 5);
    }
  }
}

extern "C" void kernel_launch(void* const* d_in, const int* in_sizes, int n_in,
                              void* d_out, int out_size, void* d_ws, size_t ws_size,
                              hipStream_t stream) {
  const float* x  = (const float*)d_in[0];
  const float* hp = (const float*)d_in[1];
  const float* L  = (const float*)d_in[2];
  const float* R  = (const float*)d_in[3];
  const float* bb = (const float*)d_in[4];
  const float* Ws = (const float*)d_in[5];
  float* out = (float*)d_out;

  __half* W16 = (__half*)d_ws;                       // 6*H*H halfs (L16 ++ R16)
  float*  f   = (float*)(W16 + 6 * HH);              // slot region

  // zero atomic accumulators (slots 0..30) + barrier area (slot30 tail).
  // ws is re-poisoned between replays, so this must run every launch.
  hipMemsetAsync(f, 0, (size_t)31 * H * sizeof(float), stream);

  mega_k<<<dim3(NBLK), dim3(256), 0, stream>>>(x, hp, L, R, bb, Ws,
                                               out, W16, f);
}

// Round 4
// 664.140 us; speedup vs baseline: 2.9441x; 1.2915x over previous
//
#include <hip/hip_runtime.h>
#include <hip/hip_fp16.h>

#define H 4096
#define HH ((size_t)H * (size_t)H)

#define OP_MUL  0
#define OP_TANH 1
#define OP_ADD  2

// ---------------------------------------------------------------------------
// Multi-dispatch version (graph-replayed boundaries are cheaper than in-kernel
// grid barriers on this harness: fixed overhead ~370us, round-0 kernels ~425us,
// round-3 fused ~480us). Phase algebra identical to the verified round-3 mega
// kernel: no zr_k (r/z1 recomputed inline), candidate 3 is identity.
// ws float-slot layout (slot = H floats) after 192 MB of fp16 mats
// (W16 = L16[3] ++ R16[3]):
//  atomic (zeroed by memset): 0-2 xL | 3-5 hL | 6-8 hR | 9-11 rR | 12-14 z1R
//    15-17 rhR | 18-20 omzR | 21-23 z2hR | 24-26 htL | 27-29 zhL
//    30: scores (6 sets x 4 floats: rh,omz,z2h,ht,zh,hn)
//  cands: 31-34 rh | 35-38 omz | 39-42 z2h | 43-46 ht | 47-50 zh | 51-54 hn
//  mixes: 57 rh | 58 omz | 59 z2h | 60 ht | 61 zh
// Dispatches:
//  memset | K1 f32 gemv L,R + fp16 convert (768) | K2 rR,z1R (768) |
//  K3 cs2 (16) | K4 rhR,omzR,z2hR mix-gemv (768) | K5 ht cands (16) |
//  K6 htL mix-gemv (768) | K7 zh cands (16) | K8 zhL mix-gemv (768) |
//  K9 hn cands (16) | K10 final (16)
// ---------------------------------------------------------------------------

__device__ __forceinline__ float sigmoidf_(float v) {
  return 1.0f / (1.0f + __expf(-v));
}

template<int NW>
__device__ __forceinline__ void reduce_atomic(float* vals, float* sc, int tid) {
  __shared__ float red[4][NW];
  const int lane = tid & 63, wv = tid >> 6;
#pragma unroll
  for (int j = 0; j < NW; ++j) {
    float v = vals[j];
#pragma unroll
    for (int off = 32; off > 0; off >>= 1) v += __shfl_down(v, off);
    if (lane == 0) red[wv][j] = v;
  }
  __syncthreads();
  if (tid < NW)
    atomicAdd(sc + tid, red[0][tid] + red[1][tid] + red[2][tid] + red[3][tid]);
}

// ---- K1: round-1 fp32 gemv over L and R + fp16 conversion. 768 blocks. ----
// mat(6) x kt(4) x rowchunk(32 of 128 rows); mats 0-2 = L (vecs x,hp ->
// slots mat / 3+mat), mats 3-5 = R (vec hp -> slot 3+mat = 6..8).
template<int NV>
__device__ __forceinline__ void p1_loop(const float* __restrict__ Mp,
                                        __half* __restrict__ M16p,
                                        const float* __restrict__ vs,
                                        float* __restrict__ f,
                                        int slot0, int slot1, int k0) {
  float acc[NV][4];
#pragma unroll
  for (int v = 0; v < NV; ++v)
#pragma unroll
    for (int j = 0; j < 4; ++j) acc[v][j] = 0.0f;
#pragma unroll 4
  for (int hh = 0; hh < 128; ++hh) {
    float4 m4 = *reinterpret_cast<const float4*>(Mp + (size_t)hh * H);
    __half c[4] = {__float2half(m4.x), __float2half(m4.y),
                   __float2half(m4.z), __float2half(m4.w)};
    *reinterpret_cast<uint2*>(M16p + (size_t)hh * H) =
        *reinterpret_cast<const uint2*>(c);
#pragma unroll
    for (int v = 0; v < NV; ++v) {
      const float s = vs[v * 128 + hh];
      acc[v][0] = fmaf(s, m4.x, acc[v][0]);
      acc[v][1] = fmaf(s, m4.y, acc[v][1]);
      acc[v][2] = fmaf(s, m4.z, acc[v][2]);
      acc[v][3] = fmaf(s, m4.w, acc[v][3]);
    }
  }
  const int slots[2] = {slot0, slot1};
#pragma unroll
  for (int v = 0; v < NV; ++v)
#pragma unroll
    for (int j = 0; j < 4; ++j)
      atomicAdd(f + (size_t)slots[v] * H + k0 + j, acc[v][j]);
}

__global__ __launch_bounds__(256) void gemv_f32_all(
    const float* __restrict__ L, const float* __restrict__ R,
    const float* __restrict__ x, const float* __restrict__ hprev,
    float* __restrict__ f, __half* __restrict__ W16) {
  const int b = blockIdx.x, t = threadIdx.x;
  const int mat = b >> 7;            // 0..5
  const int kt  = (b >> 5) & 3;
  const int r0  = (b & 31) << 7;     // 128 rows/block
  const int k0  = (kt << 10) + (t << 2);
  __shared__ float vs[256];
  if (mat < 3) {
    vs[t] = (t < 128) ? x[r0 + t] : hprev[r0 + t - 128];
  } else if (t < 128) {
    vs[t] = hprev[r0 + t];
  }
  __syncthreads();
  const size_t off = (size_t)r0 * H + k0;
  __half* M16p = W16 + (size_t)mat * HH + off;
  if (mat < 3)
    p1_loop<2>(L + (size_t)mat * HH + off, M16p, vs, f, mat, 3 + mat, k0);
  else
    p1_loop<1>(R + (size_t)(mat - 3) * HH + off, M16p, vs, f, 3 + mat, 0, k0);
}

// ---- fp16 gemv core: 64 rows, 4 halfs (8B) per thread, unroll 4. ----------
template<int NV>
__device__ __forceinline__ void gemv16_core(const __half* __restrict__ Mp,
                                            const float* __restrict__ vs,
                                            float* __restrict__ ob,
                                            int m, int k0) {
  float acc[NV][4];
#pragma unroll
  for (int v = 0; v < NV; ++v)
#pragma unroll
    for (int j = 0; j < 4; ++j) acc[v][j] = 0.0f;
#pragma unroll 4
  for (int hh = 0; hh < 64; ++hh) {
    union { uint2 u; __half2 h2[2]; } cv;
    cv.u = *reinterpret_cast<const uint2*>(Mp + (size_t)hh * H);
    float2 f0 = __half22float2(cv.h2[0]);
    float2 f1 = __half22float2(cv.h2[1]);
#pragma unroll
    for (int v = 0; v < NV; ++v) {
      const float s = vs[v * 64 + hh];
      acc[v][0] = fmaf(s, f0.x, acc[v][0]);
      acc[v][1] = fmaf(s, f0.y, acc[v][1]);
      acc[v][2] = fmaf(s, f1.x, acc[v][2]);
      acc[v][3] = fmaf(s, f1.y, acc[v][3]);
    }
  }
#pragma unroll
  for (int v = 0; v < NV; ++v)
#pragma unroll
    for (int j = 0; j < 4; ++j)
      atomicAdd(ob + (size_t)(v * 3 + m) * H + k0 + j, acc[v][j]);
}

// ---- K2: rR,z1R — 768 blocks: m(3) x kt(4) x rc(64 of 64 rows). -----------
// r/z1 recomputed inline from round-1 slots (verified in round-3).
__global__ __launch_bounds__(256) void gemv16_rz_k(
    const __half* __restrict__ R16, const float* __restrict__ f,
    const float* __restrict__ bias, float* __restrict__ ob) {
  const int b = blockIdx.x, t = threadIdx.x;
  const int m = b >> 8, kt = (b >> 6) & 3, rc = b & 63;
  const int r0 = rc << 6;
  const int k0 = (kt << 10) + (t << 2);
  __shared__ float vs[128];
  if (t < 64) {
    const int h = r0 + t;
    // r  = sigmoid(xL[1]+hR[1]+b[1]) ; z1 = sigmoid(xL[0]+hR[0]+b[0])
    vs[t]      = sigmoidf_(f[(size_t)1 * H + h] + f[(size_t)7 * H + h] + bias[H + h]);
    vs[64 + t] = sigmoidf_(f[h] + f[(size_t)6 * H + h] + bias[h]);
  }
  __syncthreads();
  gemv16_core<2>(R16 + (size_t)m * HH + (size_t)r0 * H + k0, vs, ob, m, k0);
}

__device__ __forceinline__ void write_im(const float* __restrict__ s4,
                                         float* __restrict__ dout, int os) {
  float s[4] = {s4[0], s4[1], s4[2], s4[3]};
  int idx = 0; float mx = s[0];
  for (int q = 1; q < 4; ++q) if (s[q] > mx) { mx = s[q]; idx = q; }
  float second = -1e30f;
  for (int q = 0; q < 4; ++q) if (q != idx && s[q] > second) second = s[q];
  dout[H + 3 + os] = (float)idx;
  dout[H + 9 + os] = mx - second;
}

// ---- K4/K6/K8: mix-gemv — 768 blocks: m(3) x kt(4) x rc(64 of 64 rows). ---
// Stages softmax-mixed vectors from candidates+scores; (m==0,kt==0) blocks
// store the mixed slice; block 0 writes idx/margin out-slots.
template<int NV>
__global__ __launch_bounds__(256) void gemv16_mix_k(
    const __half* __restrict__ M, const float* __restrict__ candb,
    const float* __restrict__ scb, float* __restrict__ ob,
    float* __restrict__ mixst, int os0, int os1, int os2,
    float* __restrict__ dout) {
  const int b = blockIdx.x, t = threadIdx.x;
  const int m = b >> 8, kt = (b >> 6) & 3, rc = b & 63;
  const int r0 = rc << 6;
  const int k0 = (kt << 10) + (t << 2);
  __shared__ float vs[NV * 64];
  const bool storeblk = (m == 0 && kt == 0);
  if (t < 64) {
    const int h = r0 + t;
#pragma unroll
    for (int v = 0; v < NV; ++v) {
      const float* s4 = scb + v * 4;
      float s0 = s4[0], s1 = s4[1], s2 = s4[2], s3 = s4[3];
      float mx = fmaxf(fmaxf(s0, s1), fmaxf(s2, s3));
      float e0 = __expf(s0 - mx), e1 = __expf(s1 - mx);
      float e2 = __expf(s2 - mx), e3 = __expf(s3 - mx);
      float inv = 1.0f / (e0 + e1 + e2 + e3);
      const float* cb = candb + (size_t)v * 4 * H + h;
      float mix = (e0 * cb[0] + e1 * cb[H] + e2 * cb[2 * (size_t)H] +
                   e3 * cb[3 * (size_t)H]) * inv;
      vs[v * 64 + t] = mix;
      if (storeblk) mixst[(size_t)v * H + h] = mix;
    }
  }
  if (b == 0 && t == 0) {
    const int os[3] = {os0, os1, os2};
#pragma unroll
    for (int v = 0; v < NV; ++v) write_im(scb + v * 4, dout, os[v]);
  }
  __syncthreads();
  gemv16_core<NV>(M + (size_t)m * HH + (size_t)r0 * H + k0, vs, ob, m, k0);
}

// ---- K3: cs2 — rh/omz/z2h candidates + scores. 16 blocks. -----------------
__global__ __launch_bounds__(256) void cs2_k(float* __restrict__ f,
                                             const float* __restrict__ hprev,
                                             const float* __restrict__ bias,
                                             const float* __restrict__ Ws) {
  const int t = threadIdx.x;
  const int h = (blockIdx.x << 8) + t;
  float* sc = f + 30 * (size_t)H;
  const float hp_ = hprev[h];
  const float r3 = sigmoidf_(f[(size_t)1 * H + h] + f[(size_t)7 * H + h] + bias[H + h]);
  const float z3 = sigmoidf_(f[h] + f[(size_t)6 * H + h] + bias[h]);
  const float ws = Ws[h];
  float vals[12];
#pragma unroll
  for (int l = 0; l < 3; ++l) {
    const float hl = f[(size_t)(3 + l) * H + h];
    const float rr = f[(size_t)(9 + l) * H + h];
    const float zz = f[(size_t)(12 + l) * H + h];
    const float bl = bias[(size_t)l * H + h];
    const float crh = fmaf(hl, rr, bl);
    const float com = 1.0f - (zz + bl);
    const float cz2 = fmaf(hl, zz, bl);
    f[(size_t)(31 + l) * H + h] = crh;
    f[(size_t)(35 + l) * H + h] = com;
    f[(size_t)(39 + l) * H + h] = cz2;
    vals[l] = crh * ws; vals[4 + l] = com * ws; vals[8 + l] = cz2 * ws;
  }
  {
    const float bl = bias[(size_t)3 * H + h];
    const float crh = fmaf(hp_, r3, bl);
    const float com = 1.0f - (z3 + bl);
    const float cz2 = fmaf(hp_, z3, bl);
    f[(size_t)34 * H + h] = crh;
    f[(size_t)38 * H + h] = com;
    f[(size_t)42 * H + h] = cz2;
    vals[3] = crh * ws; vals[7] = com * ws; vals[11] = cz2 * ws;
  }
  reduce_atomic<12>(vals, sc, t);
}

// ---- K5/K7/K9: generic candidate+score: c_l = op(A_l,B_l,b_l). 16 blocks. --
template<int OP>
__global__ __launch_bounds__(256) void csx_k(const float* __restrict__ A,
                                             const float* __restrict__ A3,
                                             const float* __restrict__ B,
                                             const float* __restrict__ B3,
                                             const float* __restrict__ bias,
                                             const float* __restrict__ Ws,
                                             float* __restrict__ cand,
                                             float* __restrict__ scdst) {
  const int t = threadIdx.x;
  const int h = (blockIdx.x << 8) + t;
  const float ws = Ws[h];
  float c[4];
#pragma unroll
  for (int l = 0; l < 4; ++l) {
    const float a  = (l < 3) ? A[(size_t)l * H + h] : A3[h];
    const float bv = (l < 3) ? B[(size_t)l * H + h] : B3[h];
    const float bl = bias[(size_t)l * H + h];
    if (OP == OP_MUL)  c[l] = fmaf(a, bv, bl);
    if (OP == OP_TANH) c[l] = tanhf(a + bv + bl);
    if (OP == OP_ADD)  c[l] = a + bv + bl;
    cand[(size_t)l * H + h] = c[l];
  }
  float vals[4] = {c[0] * ws, c[1] * ws, c[2] * ws, c[3] * ws};
  reduce_atomic<4>(vals, scdst, t);
}

// ---- K10: final mix -> dout. 16 blocks. -----------------------------------
__global__ __launch_bounds__(256) void final_k(const float* __restrict__ f,
                                               float* __restrict__ dout) {
  const int h = (blockIdx.x << 8) + threadIdx.x;
  const float* s4 = f + 30 * (size_t)H + 20;
  float s0 = s4[0], s1 = s4[1], s2 = s4[2], s3 = s4[3];
  float mx = fmaxf(fmaxf(s0, s1), fmaxf(s2, s3));
  float e0 = __expf(s0 - mx), e1 = __expf(s1 - mx);
  float e2 = __expf(s2 - mx), e3 = __expf(s3 - mx);
  float inv = 1.0f / (e0 + e1 + e2 + e3);
  const float* cb = f + (size_t)51 * H + h;
  dout[h] = (e0 * cb[0] + e1 * cb[H] + e2 * cb[2 * (size_t)H] +
             e3 * cb[3 * (size_t)H]) * inv;
  if (blockIdx.x == 0 && threadIdx.x == 0) {
    dout[H + 0] = 0.f; dout[H + 1] = 1.f; dout[H + 2] = 0.f;
    write_im(s4, dout, 5);
  }
}

extern "C" void kernel_launch(void* const* d_in, const int* in_sizes, int n_in,
                              void* d_out, int out_size, void* d_ws, size_t ws_size,
                              hipStream_t stream) {
  const float* x  = (const float*)d_in[0];
  const float* hp = (const float*)d_in[1];
  const float* L  = (const float*)d_in[2];
  const float* R  = (const float*)d_in[3];
  const float* bb = (const float*)d_in[4];
  const float* Ws = (const float*)d_in[5];
  float* out = (float*)d_out;

  __half* W16 = (__half*)d_ws;                       // 6*H*H halfs (L16 ++ R16)
  __half* R16 = W16 + 3 * HH;
  float*  f   = (float*)(W16 + 6 * HH);              // slot region
  float*  sc  = f + 30 * (size_t)H;

  // zero atomic accumulators (slots 0..30 incl. scores) — ws re-poisoned
  // between replays, so this runs every launch.
  hipMemsetAsync(f, 0, (size_t)31 * H * sizeof(float), stream);

  // K1: round-1 f32 gemvs + fp16 conversion
  gemv_f32_all<<<768, 256, 0, stream>>>(L, R, x, hp, f, W16);

  // K2: rR (9-11), z1R (12-14) from R16, r/z1 inline
  gemv16_rz_k<<<768, 256, 0, stream>>>(R16, f, bb, f + (size_t)9 * H);

  // K3: rh/omz/z2h candidates (31-42) + scores (sc+0..11)
  cs2_k<<<16, 256, 0, stream>>>(f, hp, bb, Ws);

  // K4: rhR,omzR,z2hR (15-23); mixes->57-59; out-slots 0,2,4
  gemv16_mix_k<3><<<768, 256, 0, stream>>>(R16, f + (size_t)31 * H, sc,
                                           f + (size_t)15 * H,
                                           f + (size_t)57 * H, 0, 2, 4, out);

  // K5: ht cands = tanh(xL + rhR + b) -> 43-46, scores sc+12
  csx_k<OP_TANH><<<16, 256, 0, stream>>>(f, x, f + (size_t)15 * H,
                                         f + (size_t)57 * H, bb, Ws,
                                         f + (size_t)43 * H, sc + 12);

  // K6: htL (24-26) from L16; mix->60; out-slot 1
  gemv16_mix_k<1><<<768, 256, 0, stream>>>(W16, f + (size_t)43 * H, sc + 12,
                                           f + (size_t)24 * H,
                                           f + (size_t)60 * H, 1, 0, 0, out);

  // K7: zh cands = htL * omzR + b -> 47-50, scores sc+16
  csx_k<OP_MUL><<<16, 256, 0, stream>>>(f + (size_t)24 * H, f + (size_t)60 * H,
                                        f + (size_t)18 * H, f + (size_t)58 * H,
                                        bb, Ws, f + (size_t)47 * H, sc + 16);

  // K8: zhL (27-29) from L16; mix->61; out-slot 3
  gemv16_mix_k<1><<<768, 256, 0, stream>>>(W16, f + (size_t)47 * H, sc + 16,
                                           f + (size_t)27 * H,
                                           f + (size_t)61 * H, 3, 0, 0, out);

  // K9: hn cands = zhL + z2hR + b -> 51-54, scores sc+20
  csx_k<OP_ADD><<<16, 256, 0, stream>>>(f + (size_t)27 * H, f + (size_t)61 * H,
                                        f + (size_t)21 * H, f + (size_t)59 * H,
                                        bb, Ws, f + (size_t)51 * H, sc + 20);

  // K10: final mix -> dout
  final_k<<<16, 256, 0, stream>>>(f, out);
}